// Round 7
// baseline (260.883 us; speedup 1.0000x reference)
//
#include <hip/hip_runtime.h>
#include <cstdint>
#include <cstddef>

#define V_TEXT   256
#define V_TOTAL  4352
#define V_AUDIO  4096
#define B_       8
#define TQ_      800
#define TK_      128
#define T_TOK    1024
#define NSEQ     32
#define K2       1.4426950408889634f   // 1/ln2
#define LN2      0.6931471805599453f
#define EM8      3.3546262790251185e-04f // e^-8 (linear blank emission)
#define FNEGINF  (-3.0e38f)
#define CHK      64                    // timesteps per LDS chunk
#define NBUF     2                     // double buffer (64 KB LDS)
#define NCE      2048                  // CE blocks in k1
#define NEMIS    200                   // emis-prep blocks in k1 (200*16384 floats)
#define EMIS_FLOATS (NSEQ * TQ_ * TK_) // 3,276,800

// ---- DPP helpers (ctrl must be a compile-time constant) ----
template <int CTRL>
__device__ __forceinline__ float dpp_mov(float x, float old) {
    return __int_as_float(__builtin_amdgcn_update_dpp(
        __float_as_int(old), __float_as_int(x), CTRL, 0xf, 0xf, false));
}
__device__ __forceinline__ float dpp_shr1_old(float x, float old) {
    return dpp_mov<0x138>(x, old);      // wave_shr:1
}
__device__ __forceinline__ float lane_bcast(float x, int lane) {
    return __int_as_float(__builtin_amdgcn_readlane(__float_as_int(x), lane));
}
__device__ __forceinline__ float wave_max(float x) {
    x = fmaxf(x, dpp_mov<0x111>(x, FNEGINF));
    x = fmaxf(x, dpp_mov<0x112>(x, FNEGINF));
    x = fmaxf(x, dpp_mov<0x114>(x, FNEGINF));
    x = fmaxf(x, dpp_mov<0x118>(x, FNEGINF));
    x = fmaxf(x, dpp_mov<0x142>(x, FNEGINF));
    x = fmaxf(x, dpp_mov<0x143>(x, FNEGINF));
    return lane_bcast(x, 63);
}
__device__ __forceinline__ float wave_sum(float x) {
    x += dpp_mov<0x111>(x, 0.0f);
    x += dpp_mov<0x112>(x, 0.0f);
    x += dpp_mov<0x114>(x, 0.0f);
    x += dpp_mov<0x118>(x, 0.0f);
    x += dpp_mov<0x142>(x, 0.0f);
    x += dpp_mov<0x143>(x, 0.0f);
    return lane_bcast(x, 63);
}

// async global->LDS, 16 B per lane: lds[base + lane*16] <- mem[g + lane*16]
// (LDS dest is wave-uniform base + lane*size per m104 -- base below is
// wave-uniform, global src is per-lane.)
__device__ __forceinline__ void gll16(const float* g, float* l) {
    __builtin_amdgcn_global_load_lds(
        (const __attribute__((address_space(1))) void*)g,
        (__attribute__((address_space(3))) void*)l, 16, 0, 0);
}

// ================= k1: CE rows + emission precompute =================
// Blocks [0,2048): CE, one wave per row (NO LDS -> full occupancy).
// Blocks [2048,2248): elementwise e = 2^(attn*K2) masked col<k -> ws_emis.
// Each emis block covers 16384 consecutive floats: 16 passes x 256 thr x 4.
__global__ __launch_bounds__(256) void ce_emis_kernel(
    const float* __restrict__ logits, const int* __restrict__ targets,
    const int* __restrict__ alens,
    const float* __restrict__ attn, const int* __restrict__ slens,
    float* __restrict__ nll_out, float* __restrict__ emis)
{
    int tid = threadIdx.x;
    int wid = tid >> 6, lane = tid & 63;

    if (blockIdx.x < NCE) {
        int row = blockIdx.x * 4 + wid;
        const float* p = logits + (size_t)row * V_TOTAL + V_TEXT;

        float4 v0 = *reinterpret_cast<const float4*>(p + lane * 4);
        float4 v1 = *reinterpret_cast<const float4*>(p + lane * 4 + 1024);
        float4 v2 = *reinterpret_cast<const float4*>(p + lane * 4 + 2048);
        float4 v3 = *reinterpret_cast<const float4*>(p + lane * 4 + 3072);
        int tg = targets[row];

        float m = fmaxf(fmaxf(fmaxf(v0.x, v0.y), fmaxf(v0.z, v0.w)),
                        fmaxf(fmaxf(v1.x, v1.y), fmaxf(v1.z, v1.w)));
        m = fmaxf(m, fmaxf(fmaxf(v2.x, v2.y), fmaxf(v2.z, v2.w)));
        m = fmaxf(m, fmaxf(fmaxf(v3.x, v3.y), fmaxf(v3.z, v3.w)));
        m = wave_max(m);

        float mn = -m * K2;
        float s =
          __builtin_exp2f(__builtin_fmaf(v0.x,K2,mn)) + __builtin_exp2f(__builtin_fmaf(v0.y,K2,mn))
        + __builtin_exp2f(__builtin_fmaf(v0.z,K2,mn)) + __builtin_exp2f(__builtin_fmaf(v0.w,K2,mn))
        + __builtin_exp2f(__builtin_fmaf(v1.x,K2,mn)) + __builtin_exp2f(__builtin_fmaf(v1.y,K2,mn))
        + __builtin_exp2f(__builtin_fmaf(v1.z,K2,mn)) + __builtin_exp2f(__builtin_fmaf(v1.w,K2,mn))
        + __builtin_exp2f(__builtin_fmaf(v2.x,K2,mn)) + __builtin_exp2f(__builtin_fmaf(v2.y,K2,mn))
        + __builtin_exp2f(__builtin_fmaf(v2.z,K2,mn)) + __builtin_exp2f(__builtin_fmaf(v2.w,K2,mn))
        + __builtin_exp2f(__builtin_fmaf(v3.x,K2,mn)) + __builtin_exp2f(__builtin_fmaf(v3.y,K2,mn))
        + __builtin_exp2f(__builtin_fmaf(v3.z,K2,mn)) + __builtin_exp2f(__builtin_fmaf(v3.w,K2,mn));
        s = wave_sum(s);

        if (lane == 0) {
            float lse = m + __builtin_log2f(s) * LN2;
            int b = row >> 10, t = row & (T_TOK - 1);
            bool valid = (t < alens[b]) && (tg != -100);
            float nll = 0.0f;
            if (valid) {
                int idx = min(max(tg - V_TEXT, 0), V_AUDIO - 1);
                nll = lse - p[idx];
            }
            nll_out[row] = nll;
        }
        return;
    }

    // ---- emission prep: 16 passes cover the full 16384-float tile (BUGFIX:
    // round 6 had u<4, leaving 3/4 of ws_emis uninitialized).
    unsigned b2 = blockIdx.x - NCE;
    unsigned base = b2 * 16384u;
    #pragma unroll
    for (int u = 0; u < 16; u++) {
        unsigned idx = base + (unsigned)(u * 256 + tid) * 4u;
        float4 v = *reinterpret_cast<const float4*>(attn + idx);
        int n   = (int)(idx / (unsigned)(TQ_ * TK_));
        int col = (int)(idx & (TK_ - 1));
        int k = min(slens[n >> 2], TK_);
        float4 e;
        e.x = (col     < k) ? __builtin_exp2f(v.x * K2) : 0.0f;
        e.y = (col + 1 < k) ? __builtin_exp2f(v.y * K2) : 0.0f;
        e.z = (col + 2 < k) ? __builtin_exp2f(v.z * K2) : 0.0f;
        e.w = (col + 3 < k) ? __builtin_exp2f(v.w * K2) : 0.0f;
        *reinterpret_cast<float4*>(emis + idx) = e;
    }
}

// ================= k2: CTC recursion alone (no CE contention) ============
// 4 waves: wave 0 = consumer (scaled-linear recursion); waves 1-3 stage the
// next 64-row chunk of precomputed emissions via global_load_lds (double
// buffer) and accumulate the softmax normalizer Csum from LDS re-reads.
__global__ __launch_bounds__(256) void rec_kernel(
    const float* __restrict__ emis,
    const int* __restrict__ slens, const int* __restrict__ olens,
    float* __restrict__ loss_out)
{
    __shared__ float buf[NBUF][CHK][TK_];   // 65536 B
    __shared__ float cshp[4];
    int n   = blockIdx.x;
    int tid = threadIdx.x;
    int wid = tid >> 6, lane = tid & 63;
    int k = min(slens[n >> 2], TK_);
    int q = min(olens[n >> 2], TQ_);
    int ncha = (q + CHK - 1) / CHK;          // 7..13
    const float* ebase = emis + (size_t)n * (TQ_ * TK_);

    float prod = 1.0f;   // Csum mantissa-product (uniform across lanes)
    int   acc  = 0;

    // consumer state: lane l holds states 4l..4l+3 (p0..p3); p4 = state 256
    // (lane 63). Virtual pre-state p0=1 on lane 0 makes t=0 a regular step.
    float p0 = (wid == 0 && lane == 0) ? 1.0f : 0.0f;
    float p1 = 0.0f, p2 = 0.0f, p3 = 0.0f, p4 = 0.0f, p3s = 0.0f;
    int   Mtot = 0;

#define STAGE(ch)                                                            \
    do {                                                                     \
        const float* gb = ebase + (size_t)(ch) * CHK * TK_;                  \
        float* lb = &buf[(ch) & 1][0][0];                                    \
        _Pragma("unroll")                                                    \
        for (int u = 0; u < 11; u++) {                                       \
            int kk = 3 * u + (wid - 1);                                      \
            if (kk < 32 && (ch) * CHK + 2 * kk < TQ_)                        \
                gll16(gb + kk * 256 + lane * 4, lb + kk * 256);              \
        }                                                                    \
    } while (0)

    if (wid > 0) {
        STAGE(0);
        asm volatile("s_waitcnt vmcnt(0)" ::: "memory");
    }
    __builtin_amdgcn_s_barrier();
    asm volatile("" ::: "memory");

#define SSTEP(xv)                                                            \
    do {                                                                     \
        float c01 = p0 + p3s;                                                \
        float c12 = p2 + p1;                                                 \
        float n4  = (p4 + p3) * EM8;                                         \
        p0 = c01 * EM8;                                                      \
        p1 = (p1 + c01) * xv.x;                                              \
        p2 = c12 * EM8;                                                      \
        p3 = (p3 + c12) * xv.y;                                              \
        p4 = n4;                                                             \
        p3s = dpp_shr1_old(p3, 0.0f);                                        \
    } while (0)

    for (int c = 0; c < ncha; c++) {
        if (wid > 0) {
            if (c + 1 < ncha) STAGE(c + 1);
            // Csum over this chunk's rows (LDS re-read; hidden under consumer)
            const float* cb = &buf[c & 1][0][0];
            for (int i = 0; i < 22; i++) {
                int r = (wid - 1) + 3 * i;
                if (r >= CHK) break;
                int rg = c * CHK + r;
                float2 xv = *reinterpret_cast<const float2*>(cb + r * TK_ + 2 * lane);
                float ps = wave_sum(xv.x + xv.y) + EM8;
                prod *= (rg < q) ? ps : 1.0f;
                if (i & 1) {               // exact renorm every 2 multiplies
                    int b = __float_as_int(prod);
                    acc += (b >> 23) - 127;
                    prod = __int_as_float((b & 0x007fffff) | 0x3f800000);
                }
            }
            asm volatile("s_waitcnt vmcnt(0) lgkmcnt(0)" ::: "memory");
        } else {
            const float* lb2 = &buf[c & 1][0][2 * lane];
            int lim = min(CHK, q - c * CHK);
            int nfull = lim >> 3, rem = lim & 7;
            float2 cur[8], nxt[8];
            #pragma unroll
            for (int j = 0; j < 8; j++)
                cur[j] = *reinterpret_cast<const float2*>(lb2 + j * TK_);
            for (int g = 0; g < nfull; g++) {
                int base = g * 8;
                #pragma unroll
                for (int j = 0; j < 8; j++)
                    nxt[j] = *reinterpret_cast<const float2*>(
                        lb2 + min(base + 8 + j, CHK - 1) * TK_);
                // off-chain rescale: snapshot max BEFORE the group; DPP tree
                // overlaps the 8 SSTEPs; apply power-of-2 scale after.
                float wm = fmaxf(fmaxf(fmaxf(p0, p1), fmaxf(p2, p3)),
                                 fmaxf(p4, p3s));
                #pragma unroll
                for (int j = 0; j < 8; j++) SSTEP(cur[j]);
                wm = fmaxf(wm, dpp_mov<0x111>(wm, FNEGINF));
                wm = fmaxf(wm, dpp_mov<0x112>(wm, FNEGINF));
                wm = fmaxf(wm, dpp_mov<0x114>(wm, FNEGINF));
                wm = fmaxf(wm, dpp_mov<0x118>(wm, FNEGINF));
                wm = fmaxf(wm, dpp_mov<0x142>(wm, FNEGINF));
                wm = fmaxf(wm, dpp_mov<0x143>(wm, FNEGINF));
                wm = lane_bcast(wm, 63);
                int ebits = __float_as_int(wm) & 0x7f800000;
                if (ebits > 0) {            // park snapshot-max at 2^-32:
                    int se = 222 - (ebits >> 23);   // bound: |p| <= 2^45
                    se = se < 1 ? 1 : (se > 254 ? 254 : se);
                    float sc = __int_as_float(se << 23);
                    Mtot += 127 - se;
                    p0 *= sc; p1 *= sc; p2 *= sc; p3 *= sc; p4 *= sc; p3s *= sc;
                }
                #pragma unroll
                for (int j = 0; j < 8; j++) cur[j] = nxt[j];
            }
            #pragma unroll
            for (int j = 0; j < 8; j++) if (j < rem) SSTEP(cur[j]);
            asm volatile("s_waitcnt lgkmcnt(0)" ::: "memory");
        }
        __builtin_amdgcn_s_barrier();
        asm volatile("" ::: "memory");
    }
#undef SSTEP
#undef STAGE

    if (wid > 0) {
        float cl = __builtin_log2f(prod) + (float)acc;   // uniform
        if (lane == 0) cshp[wid] = cl;
    }
    __syncthreads();

    if (wid == 0) {
        float csh = cshp[1] + cshp[2] + cshp[3];
        int s1 = 2 * k - 1, s2 = 2 * k;
        float e1v, e2v;
        {
            int l = s1 >> 2, r = s1 & 3;
            float c1 = __shfl(p1, l), c3 = __shfl(p3, l);
            e1v = (r == 1) ? c1 : c3;
        }
        if (s2 == 256) {
            e2v = __shfl(p4, 63);
        } else {
            int l = s2 >> 2, r = s2 & 3;
            float c0 = __shfl(p0, l), c2 = __shfl(p2, l);
            e2v = (r == 0) ? c0 : c2;
        }
        float l2 = __builtin_log2f(e1v + e2v) + (float)Mtot - csh;
        float nll = -l2 * LN2;
        float loss = nll / (float)k;
        if (!(isfinite(loss) && loss < 1.0e8f)) loss = 0.0f;
        if (lane == 0) loss_out[n] = loss;
    }
}

// ================= fallback (round-5 fused kernel, used if ws too small) ==
__device__ __forceinline__ void lds_barrier() {
    asm volatile("s_waitcnt lgkmcnt(0)" ::: "memory");
    __builtin_amdgcn_s_barrier();
    asm volatile("" ::: "memory");
}
__device__ __forceinline__ void load6(float4* v, const float* __restrict__ abase,
                                      int g0, int pw, int lane) {
    int half = lane >> 5, col = (lane & 31) * 4;
    int i0 = pw * 5;
    #pragma unroll
    for (int u = 0; u < 6; u++) {
        int rc = min(g0 + 2 * (i0 + u) + half, TQ_ - 1);
        v[u] = *reinterpret_cast<const float4*>(abase + (size_t)rc * TK_ + col);
    }
}
__device__ __forceinline__ void write6(float* db, const float4* v, int g0, int pw,
                                       int k, int q, int lane, float& prod, int& acc) {
    int half = lane >> 5, col = (lane & 31) * 4;
    int i0 = pw * 5;
    #pragma unroll
    for (int u = 0; u < 6; u++) {
        int r  = 2 * (i0 + u) + half;
        int rg = g0 + r;
        float e0 = (col + 0 < k) ? __builtin_exp2f(v[u].x * K2) : 0.0f;
        float e1 = (col + 1 < k) ? __builtin_exp2f(v[u].y * K2) : 0.0f;
        float e2 = (col + 2 < k) ? __builtin_exp2f(v[u].z * K2) : 0.0f;
        float e3 = (col + 3 < k) ? __builtin_exp2f(v[u].w * K2) : 0.0f;
        *reinterpret_cast<float4*>(db + r * TK_ + col) = make_float4(e0, e1, e2, e3);
        float ps = (e0 + e1) + (e2 + e3);
        ps += dpp_mov<0x111>(ps, 0.0f);
        ps += dpp_mov<0x112>(ps, 0.0f);
        ps += dpp_mov<0x114>(ps, 0.0f);
        ps += dpp_mov<0x118>(ps, 0.0f);
        ps += dpp_mov<0x142>(ps, 0.0f);
        ps += EM8;
        bool owned = (u < 5) || (pw == 2);
        prod *= (owned && rg < q) ? ps : 1.0f;
        if (u & 1) {
            int b = __float_as_int(prod);
            acc += (b >> 23) - 127;
            prod = __int_as_float((b & 0x007fffff) | 0x3f800000);
        }
    }
}
#define FCHK 32
__global__ __launch_bounds__(256) void fused_fallback(
    const float* __restrict__ logits, const int* __restrict__ targets,
    const int* __restrict__ alens,
    const float* __restrict__ attn, const int* __restrict__ slens,
    const int* __restrict__ olens,
    float* __restrict__ nll_out, float* __restrict__ loss_out)
{
    __shared__ float buf[3][FCHK][TK_];
    __shared__ float cshp[4];
    int tid = threadIdx.x;
    int wid = tid >> 6, lane = tid & 63;
    if (blockIdx.x >= NSEQ) {
        int row = (blockIdx.x - NSEQ) * 4 + wid;
        const float* p = logits + (size_t)row * V_TOTAL + V_TEXT;
        float4 v0 = *reinterpret_cast<const float4*>(p + lane * 4);
        float4 v1 = *reinterpret_cast<const float4*>(p + lane * 4 + 1024);
        float4 v2 = *reinterpret_cast<const float4*>(p + lane * 4 + 2048);
        float4 v3 = *reinterpret_cast<const float4*>(p + lane * 4 + 3072);
        int tg = targets[row];
        float m = fmaxf(fmaxf(fmaxf(v0.x, v0.y), fmaxf(v0.z, v0.w)),
                        fmaxf(fmaxf(v1.x, v1.y), fmaxf(v1.z, v1.w)));
        m = fmaxf(m, fmaxf(fmaxf(v2.x, v2.y), fmaxf(v2.z, v2.w)));
        m = fmaxf(m, fmaxf(fmaxf(v3.x, v3.y), fmaxf(v3.z, v3.w)));
        m = wave_max(m);
        float mn = -m * K2;
        float s =
          __builtin_exp2f(__builtin_fmaf(v0.x,K2,mn)) + __builtin_exp2f(__builtin_fmaf(v0.y,K2,mn))
        + __builtin_exp2f(__builtin_fmaf(v0.z,K2,mn)) + __builtin_exp2f(__builtin_fmaf(v0.w,K2,mn))
        + __builtin_exp2f(__builtin_fmaf(v1.x,K2,mn)) + __builtin_exp2f(__builtin_fmaf(v1.y,K2,mn))
        + __builtin_exp2f(__builtin_fmaf(v1.z,K2,mn)) + __builtin_exp2f(__builtin_fmaf(v1.w,K2,mn))
        + __builtin_exp2f(__builtin_fmaf(v2.x,K2,mn)) + __builtin_exp2f(__builtin_fmaf(v2.y,K2,mn))
        + __builtin_exp2f(__builtin_fmaf(v2.z,K2,mn)) + __builtin_exp2f(__builtin_fmaf(v2.w,K2,mn))
        + __builtin_exp2f(__builtin_fmaf(v3.x,K2,mn)) + __builtin_exp2f(__builtin_fmaf(v3.y,K2,mn))
        + __builtin_exp2f(__builtin_fmaf(v3.z,K2,mn)) + __builtin_exp2f(__builtin_fmaf(v3.w,K2,mn));
        s = wave_sum(s);
        if (lane == 0) {
            float lse = m + __builtin_log2f(s) * LN2;
            int b = row >> 10, t = row & (T_TOK - 1);
            bool valid = (t < alens[b]) && (tg != -100);
            float nll = 0.0f;
            if (valid) {
                int idx = min(max(tg - V_TEXT, 0), V_AUDIO - 1);
                nll = lse - p[idx];
            }
            nll_out[row] = nll;
        }
        return;
    }
    int n = blockIdx.x;
    int k = min(slens[n >> 2], TK_);
    int q = min(olens[n >> 2], TQ_);
    int ncha = (q + FCHK - 1) / FCHK;
    const float* abase = attn + (size_t)n * TQ_ * TK_;
    float prod = 1.0f; int acc = 0;
    float p0 = (wid == 0 && lane == 0) ? 1.0f : 0.0f;
    float p1 = 0.0f, p2 = 0.0f, p3 = 0.0f, p4 = 0.0f, p3s = 0.0f;
    int Mtot = 0;
    float4 R0[6], R1[6];
    if (wid > 0) {
        load6(R0, abase, 0,        wid - 1, lane);
        load6(R1, abase, FCHK,     wid - 1, lane);
        write6(&buf[0][0][0], R0, 0, wid - 1, k, q, lane, prod, acc);
        load6(R0, abase, 2 * FCHK, wid - 1, lane);
    }
    lds_barrier();
#define SSTEP(xv)                                                            \
    do {                                                                     \
        float c01 = p0 + p3s;                                                \
        float c12 = p2 + p1;                                                 \
        float n4  = (p4 + p3) * EM8;                                         \
        p0 = c01 * EM8;                                                      \
        p1 = (p1 + c01) * xv.x;                                              \
        p2 = c12 * EM8;                                                      \
        p3 = (p3 + c12) * xv.y;                                              \
        p4 = n4;                                                             \
        p3s = dpp_shr1_old(p3, 0.0f);                                        \
    } while (0)
    for (int c = 0; c < ncha; c++) {
        if (wid > 0) {
            if (c + 1 < ncha) {
                float* db = &buf[(c + 1) % 3][0][0];
                if ((c + 1) & 1) write6(db, R1, (c + 1) * FCHK, wid - 1, k, q, lane, prod, acc);
                else             write6(db, R0, (c + 1) * FCHK, wid - 1, k, q, lane, prod, acc);
            }
            if (c + 3 < ncha) {
                if ((c + 3) & 1) load6(R1, abase, (c + 3) * FCHK, wid - 1, lane);
                else             load6(R0, abase, (c + 3) * FCHK, wid - 1, lane);
            }
        } else {
            const float* lb = &buf[c % 3][0][2 * lane];
            int lim = min(FCHK, q - c * FCHK);
            int nfull = lim >> 3, rem = lim & 7;
            float2 cur[8], nxt[8];
            #pragma unroll
            for (int j = 0; j < 8; j++)
                cur[j] = *reinterpret_cast<const float2*>(lb + min(j, FCHK - 1) * TK_);
            for (int g = 0; g < nfull; g++) {
                int base = g * 8;
                #pragma unroll
                for (int j = 0; j < 8; j++)
                    nxt[j] = *reinterpret_cast<const float2*>(lb + min(base + 8 + j, FCHK - 1) * TK_);
                float wm = fmaxf(fmaxf(fmaxf(p0, p1), fmaxf(p2, p3)),
                                 fmaxf(p4, p3s));
                #pragma unroll
                for (int j = 0; j < 8; j++) SSTEP(cur[j]);
                wm = fmaxf(wm, dpp_mov<0x111>(wm, FNEGINF));
                wm = fmaxf(wm, dpp_mov<0x112>(wm, FNEGINF));
                wm = fmaxf(wm, dpp_mov<0x114>(wm, FNEGINF));
                wm = fmaxf(wm, dpp_mov<0x118>(wm, FNEGINF));
                wm = fmaxf(wm, dpp_mov<0x142>(wm, FNEGINF));
                wm = fmaxf(wm, dpp_mov<0x143>(wm, FNEGINF));
                wm = lane_bcast(wm, 63);
                int ebits = __float_as_int(wm) & 0x7f800000;
                if (ebits > 0) {
                    int se = 222 - (ebits >> 23);
                    se = se < 1 ? 1 : (se > 254 ? 254 : se);
                    float sc = __int_as_float(se << 23);
                    Mtot += 127 - se;
                    p0 *= sc; p1 *= sc; p2 *= sc; p3 *= sc; p4 *= sc; p3s *= sc;
                }
                #pragma unroll
                for (int j = 0; j < 8; j++) cur[j] = nxt[j];
            }
            #pragma unroll
            for (int j = 0; j < 8; j++) if (j < rem) SSTEP(cur[j]);
        }
        lds_barrier();
    }
#undef SSTEP
    if (wid > 0) {
        float cl = __builtin_log2f(prod) + (float)acc;
        float cs = lane_bcast(cl, 31) + lane_bcast(cl, 63);
        if (lane == 0) cshp[wid] = cs;
    }
    __syncthreads();
    if (wid == 0) {
        float csh = cshp[1] + cshp[2] + cshp[3];
        int s1 = 2 * k - 1, s2 = 2 * k;
        float e1v, e2v;
        {
            int l = s1 >> 2, r = s1 & 3;
            float c1 = __shfl(p1, l), c3 = __shfl(p3, l);
            e1v = (r == 1) ? c1 : c3;
        }
        if (s2 == 256) {
            e2v = __shfl(p4, 63);
        } else {
            int l = s2 >> 2, r = s2 & 3;
            float c0 = __shfl(p0, l), c2 = __shfl(p2, l);
            e2v = (r == 0) ? c0 : c2;
        }
        float l2 = __builtin_log2f(e1v + e2v) + (float)Mtot - csh;
        float nll = -l2 * LN2;
        float loss = nll / (float)k;
        if (!(isfinite(loss) && loss < 1.0e8f)) loss = 0.0f;
        if (lane == 0) loss_out[n] = loss;
    }
}

// ---------- finalize ----------
__global__ __launch_bounds__(256) void fin_kernel(
    const float* __restrict__ nll, const int* __restrict__ alens,
    const int* __restrict__ step, const float* __restrict__ attn_losses,
    float* __restrict__ out)
{
    __shared__ float red[4];
    int tid = threadIdx.x;
    float s = 0.0f;
    for (int i = tid; i < B_ * T_TOK; i += 256) s += nll[i];
    #pragma unroll
    for (int off = 32; off > 0; off >>= 1) s += __shfl_xor(s, off);
    if ((tid & 63) == 0) red[tid >> 6] = s;
    __syncthreads();
    if (tid == 0) {
        float ce_sum = red[0] + red[1] + red[2] + red[3];
        int denom = 0;
        for (int b = 0; b < B_; b++) denom += min(alens[b], T_TOK);
        denom = max(denom, 1);
        float token = ce_sum / (float)denom;
        float a = 0.0f;
        for (int i = 0; i < NSEQ; i++) a += attn_losses[i];
        a *= (1.0f / NSEQ);
        if (step[0] <= 5000) a = 0.0f;
        out[0] = 1.5f * token + 10.0f * a;
        out[1] = a;
        out[2] = token;
    }
}

extern "C" void kernel_launch(void* const* d_in, const int* in_sizes, int n_in,
                              void* d_out, int out_size, void* d_ws, size_t ws_size,
                              hipStream_t stream)
{
    const float* logits  = (const float*)d_in[0];
    const float* attn    = (const float*)d_in[1];
    const int*   targets = (const int*)d_in[2];
    const int*   alens   = (const int*)d_in[3];
    const int*   slens   = (const int*)d_in[4];
    const int*   olens   = (const int*)d_in[5];
    const int*   step    = (const int*)d_in[6];
    float* out = (float*)d_out;
    float* ws  = (float*)d_ws;

    float* ws_attn = ws;            // [0..31]
    float* ws_nll  = ws + 64;       // [64 .. 64+8192)
    float* ws_emis = ws + 16384;    // [16384 .. +3,276,800)

    size_t need = (size_t)(16384 + EMIS_FLOATS) * sizeof(float);
    if (ws_size >= need) {
        ce_emis_kernel<<<dim3(NCE + NEMIS), dim3(256), 0, stream>>>(
            logits, targets, alens, attn, slens, ws_nll, ws_emis);
        rec_kernel<<<dim3(NSEQ), dim3(256), 0, stream>>>(
            ws_emis, slens, olens, ws_attn);
    } else {
        fused_fallback<<<dim3(NSEQ + NCE), dim3(256), 0, stream>>>(
            logits, targets, alens, attn, slens, olens, ws_nll, ws_attn);
    }
    fin_kernel<<<dim3(1), dim3(256), 0, stream>>>(ws_nll, alens, step, ws_attn, out);
}